// Round 5
// baseline (345.722 us; speedup 1.0000x reference)
//
#include <hip/hip_runtime.h>
#include <hip/hip_fp16.h>

#define N_NODES 100000
#define N_EDGES 1250000
#define F 64
#define SCAN_CHUNK 1024
#define NBLK_SCAN ((N_NODES + SCAN_CHUNK - 1) / SCAN_CHUNK)  // 98
#define GPW 4    // nodes per wave
#define NPB 32   // nodes per block (8 waves * GPW)
#define TP  33   // pad: column writes (lane*33+n)%32 -> <=2-way (free)

// ---------------- K0: convert x->fp16, pack weights->half2, hist, idx pad ----
// counts must be zeroed by a prior memset (hist atomics race with in-kernel zeroing).
template<bool HALFX>
__global__ __launch_bounds__(256) void conv_hist_kernel(
    const float4* __restrict__ x4, const int* __restrict__ ei,
    const float* __restrict__ ew,
    __half* __restrict__ xh, __half2* __restrict__ wpk,
    int* __restrict__ idx, int* __restrict__ counts)
{
    int gid = blockIdx.x * 256 + threadIdx.x;
    if (HALFX) {
        if (gid < N_NODES * F / 4) {
            float4 v = x4[gid];
            __half2 h01 = __floats2half2_rn(v.x, v.y);
            __half2 h23 = __floats2half2_rn(v.z, v.w);
            int2 pk;
            pk.x = *(const int*)&h01;
            pk.y = *(const int*)&h23;
            ((int2*)xh)[gid] = pk;
        }
    }
    if (gid < N_EDGES) {
        wpk[gid] = __floats2half2_rn(ew[gid], ew[N_EDGES + gid]);
        atomicAdd(&counts[ei[N_EDGES + gid]], 1);
    }
    if (gid < 16) idx[N_EDGES + gid] = 0;  // sentinel pad: valid edge id
}

// ---------------- K1: per-1024-chunk partial sums ----------------
__global__ __launch_bounds__(256) void scan_reduce_kernel(const int* __restrict__ counts,
                                                          int* __restrict__ partials) {
    int base = blockIdx.x * SCAN_CHUNK + threadIdx.x * 4;
    int s = 0;
    if (base + 3 < N_NODES) {
        int4 c = *(const int4*)&counts[base];
        s = c.x + c.y + c.z + c.w;
    }
    for (int d = 32; d > 0; d >>= 1) s += __shfl_down(s, d);
    __shared__ int lds[4];
    int lane = threadIdx.x & 63, wave = threadIdx.x >> 6;
    if (lane == 0) lds[wave] = s;
    __syncthreads();
    if (threadIdx.x == 0) partials[blockIdx.x] = lds[0] + lds[1] + lds[2] + lds[3];
}

// ---------------- K2: per-chunk exclusive scan -> off + cursor ----------------
__global__ __launch_bounds__(256) void scan_apply_kernel(const int* __restrict__ counts,
                                                         const int* __restrict__ partials,
                                                         int* __restrict__ off,
                                                         int* __restrict__ cursor) {
    __shared__ int sh_red[4];
    __shared__ int sh_base;
    __shared__ int wsum[4];
    int t = threadIdx.x;
    int lane = t & 63, wave = t >> 6;

    int pp = 0;
    if (t < blockIdx.x && t < NBLK_SCAN) pp = partials[t];
    for (int d = 32; d > 0; d >>= 1) pp += __shfl_down(pp, d);
    if (lane == 0) sh_red[wave] = pp;
    __syncthreads();
    if (t == 0) sh_base = sh_red[0] + sh_red[1] + sh_red[2] + sh_red[3];

    int base = blockIdx.x * SCAN_CHUNK + t * 4;
    int4 c = {0, 0, 0, 0};
    bool act = (base + 3 < N_NODES);
    if (act) c = *(const int4*)&counts[base];
    int s = c.x + c.y + c.z + c.w;

    int xs = s;
    for (int d = 1; d < 64; d <<= 1) {
        int y = __shfl_up(xs, d);
        if (lane >= d) xs += y;
    }
    if (lane == 63) wsum[wave] = xs;
    __syncthreads();
    int pre = xs - s;
    for (int w = 0; w < wave; ++w) pre += wsum[w];
    pre += sh_base;

    if (act) {
        int o0 = pre, o1 = o0 + c.x, o2 = o1 + c.y, o3 = o2 + c.z;
        int4 o = {o0, o1, o2, o3};
        *(int4*)&off[base] = o;
        *(int4*)&cursor[base] = o;
        if (base + 4 == N_NODES) off[N_NODES] = o3 + c.w;  // == N_EDGES
    }
}

// ---------------- K3: scatter edge IDs only (4B per edge) ----------------
__global__ __launch_bounds__(256) void permute_kernel(const int* __restrict__ ei,
                                                      int* __restrict__ cursor,
                                                      int* __restrict__ idx) {
    int e = blockIdx.x * 256 + threadIdx.x;
    if (e >= N_EDGES) return;
    int r = ei[N_EDGES + e];
    int pos = atomicAdd(&cursor[r], 1);
    idx[pos] = e;
}

// ---------------- K4: fused aggregation + GEMM ----------------
// 512 threads = 8 waves x GPW=4 nodes. 3-stage pipelined edge loop:
//   stage A: eids (sequential, for batch t+2)
//   stage B: src/w broadcasts from eids loaded 1 iter ago (batch t+1... t+2)
//   stage C: x-row gather from srcs loaded 1 iter ago (batch t+1)
// each random load class gets >=1 full iteration of latency cover. idx is
// padded with 16 valid sentinel ids so the hot loop needs no bounds guards.
template<bool HALFX>
__global__ __launch_bounds__(512, 4) void agg_gemm_kernel(
    const float* __restrict__ x, const __half* __restrict__ xh,
    const int* __restrict__ off, const int* __restrict__ idx,
    const int* __restrict__ ei, const __half2* __restrict__ wpk,
    const float* __restrict__ Wsrc, const float* __restrict__ Wdst,
    const float* __restrict__ bsrc, const float* __restrict__ bdst,
    float* __restrict__ outA, float* __restrict__ outB)
{
    __shared__ float tA[F * TP];
    __shared__ float tB[F * TP];
    int t = threadIdx.x;
    int w = t >> 6;
    int lane = t & 63;
    int n0 = blockIdx.x * NPB + w * GPW;
    int nIB0 = w * GPW;

    int b[GPW + 1];
    #pragma unroll
    for (int j = 0; j <= GPW; ++j) b[j] = off[n0 + j];

    int i = b[0];
    const int end = b[GPW];
    int cur = 0;
    int next_b = b[1];
    float accA = 0.f, accB = 0.f;

#define XLOAD(s) (HALFX ? __half2float(xh[(size_t)(s) * F + lane]) \
                        : x[(size_t)(s) * F + lane])
#define FLUSH() { tA[lane * TP + nIB0 + cur] = accA;                  \
                  tB[lane * TP + nIB0 + cur] = accB;                  \
                  accA = 0.f; accB = 0.f; ++cur;                      \
                  next_b = (cur < GPW) ? b[cur + 1] : 0x7fffffff; }

    // pipeline state: vC/wC = batch i (ready); srcA/wA = batch i+4; eidA = batch i+8
    float vC[4]; __half2 wC[4];
    int srcA[4]; __half2 wA[4];
    int eidA[4];
    {
        int e0[4], e1[4];
        #pragma unroll
        for (int j = 0; j < 4; ++j) e0[j] = idx[i + j];
        #pragma unroll
        for (int j = 0; j < 4; ++j) e1[j] = idx[i + 4 + j];
        #pragma unroll
        for (int j = 0; j < 4; ++j) eidA[j] = idx[i + 8 + j];
        int s0[4];
        #pragma unroll
        for (int j = 0; j < 4; ++j) { s0[j] = ei[e0[j]]; wC[j] = wpk[e0[j]]; }
        #pragma unroll
        for (int j = 0; j < 4; ++j) { srcA[j] = ei[e1[j]]; wA[j] = wpk[e1[j]]; }
        #pragma unroll
        for (int j = 0; j < 4; ++j) vC[j] = XLOAD(s0[j]);
    }

    while (i + 4 <= end) {
        int eidB[4]; int srcB[4]; __half2 wB[4]; float vA4[4];
        #pragma unroll
        for (int j = 0; j < 4; ++j) eidB[j] = idx[i + 12 + j];        // batch i+12
        #pragma unroll
        for (int j = 0; j < 4; ++j) { srcB[j] = ei[eidA[j]]; wB[j] = wpk[eidA[j]]; }  // batch i+8
        #pragma unroll
        for (int j = 0; j < 4; ++j) vA4[j] = XLOAD(srcA[j]);          // batch i+4
        #pragma unroll
        for (int j = 0; j < 4; ++j) {
            while (i + j == next_b) FLUSH();
            float2 wf = __half22float2(wC[j]);
            accA += vC[j] * wf.x; accB += vC[j] * wf.y;
        }
        i += 4;
        #pragma unroll
        for (int j = 0; j < 4; ++j) {
            vC[j] = vA4[j]; wC[j] = wA[j];
            srcA[j] = srcB[j]; wA[j] = wB[j]; eidA[j] = eidB[j];
        }
    }
    while (i < end) {  // tail <4 edges: direct scalar loads
        while (i == next_b) FLUSH();
        int e = idx[i];
        __half2 wv = wpk[e];
        int s = ei[e];
        float v = XLOAD(s);
        float2 wf = __half22float2(wv);
        accA += v * wf.x; accB += v * wf.y;
        ++i;
    }
    while (cur < GPW) FLUSH();
#undef FLUSH
#undef XLOAD

    __syncthreads();

    // GEMM phase: 256 active threads; dir = t>>7; 4 nodes x 4 feats per thread.
    if (t < 256) {
        int dir = t >> 7;
        int tx = t & 15, ty = (t >> 4) & 7;
        int j4 = tx * 4, n4 = ty * 4;
        const float* W    = dir ? Wdst : Wsrc;
        const float* bias = dir ? bdst : bsrc;
        const float* tile = dir ? tB : tA;
        float* out        = dir ? outB : outA;

        float4 bj = *(const float4*)&bias[j4];
        float4 a0 = bj, a1 = bj, a2 = bj, a3 = bj;
        #pragma unroll 8
        for (int k = 0; k < F; ++k) {
            float4 wv = *(const float4*)&W[k * F + j4];
            float v0 = tile[k * TP + n4 + 0];
            float v1 = tile[k * TP + n4 + 1];
            float v2 = tile[k * TP + n4 + 2];
            float v3 = tile[k * TP + n4 + 3];
            a0.x += v0 * wv.x; a0.y += v0 * wv.y; a0.z += v0 * wv.z; a0.w += v0 * wv.w;
            a1.x += v1 * wv.x; a1.y += v1 * wv.y; a1.z += v1 * wv.z; a1.w += v1 * wv.w;
            a2.x += v2 * wv.x; a2.y += v2 * wv.y; a2.z += v2 * wv.z; a2.w += v2 * wv.w;
            a3.x += v3 * wv.x; a3.y += v3 * wv.y; a3.z += v3 * wv.z; a3.w += v3 * wv.w;
        }
        int nb = blockIdx.x * NPB + n4;
        *(float4*)&out[(size_t)(nb + 0) * F + j4] = a0;
        *(float4*)&out[(size_t)(nb + 1) * F + j4] = a1;
        *(float4*)&out[(size_t)(nb + 2) * F + j4] = a2;
        *(float4*)&out[(size_t)(nb + 3) * F + j4] = a3;
    }
}

// ---------------- fallback path (atomic) ----------------

__global__ __launch_bounds__(256) void scatter_fallback(const float4* __restrict__ x4,
                                                        const int* __restrict__ ei,
                                                        const float* __restrict__ ew,
                                                        float* __restrict__ aggA,
                                                        float* __restrict__ aggB) {
    int t = blockIdx.x * blockDim.x + threadIdx.x;
    int e = t >> 4;
    int lane16 = t & 15;
    if (e >= N_EDGES) return;
    int src = ei[e], dst = ei[N_EDGES + e];
    float w0 = ew[e], w1 = ew[N_EDGES + e];
    float4 v = x4[(size_t)src * 16 + lane16];
    int base = dst * F + lane16 * 4;
    atomicAdd(&aggA[base + 0], v.x * w0); atomicAdd(&aggA[base + 1], v.y * w0);
    atomicAdd(&aggA[base + 2], v.z * w0); atomicAdd(&aggA[base + 3], v.w * w0);
    atomicAdd(&aggB[base + 0], v.x * w1); atomicAdd(&aggB[base + 1], v.y * w1);
    atomicAdd(&aggB[base + 2], v.z * w1); atomicAdd(&aggB[base + 3], v.w * w1);
}

__global__ __launch_bounds__(256) void matmul_fallback(float* __restrict__ outA, float* __restrict__ outB,
                                                       const float* __restrict__ Wsrc, const float* __restrict__ Wdst,
                                                       const float* __restrict__ bsrc, const float* __restrict__ bdst) {
    __shared__ float lWs[F * F];
    __shared__ float lWd[F * F];
    for (int i = threadIdx.x; i < F * F / 4; i += blockDim.x) {
        ((float4*)lWs)[i] = ((const float4*)Wsrc)[i];
        ((float4*)lWd)[i] = ((const float4*)Wdst)[i];
    }
    __syncthreads();
    int wave = (blockIdx.x * blockDim.x + threadIdx.x) >> 6;
    int lane = threadIdx.x & 63;
    if (wave >= N_NODES) return;
    size_t rowbase = (size_t)wave * F;
    float a0 = outA[rowbase + lane], a1 = outB[rowbase + lane];
    float acc0 = bsrc[lane], acc1 = bdst[lane];
    #pragma unroll
    for (int k = 0; k < F; ++k) {
        acc0 += __shfl(a0, k) * lWs[k * F + lane];
        acc1 += __shfl(a1, k) * lWd[k * F + lane];
    }
    outA[rowbase + lane] = acc0;
    outB[rowbase + lane] = acc1;
}

// ---------------- launch ----------------

template<bool HALFX>
static void run_path(const float* x, const int* ei, const float* ew,
                     const float* Wsrc, const float* Wdst,
                     const float* bsrc, const float* bdst,
                     float* outA, float* outB, char* ws, hipStream_t stream) {
    // ws layout (all offsets multiples of 128)
    int*     counts   = (int*)(ws + 0);          // 400128
    int*     off      = (int*)(ws + 400128);     // 400640
    int*     cursor   = (int*)(ws + 800768);     // 400128
    int*     partials = (int*)(ws + 1200896);    // 512
    int*     idx      = (int*)(ws + 1201408);    // (E+16)*4 -> 5000192
    __half2* wpk      = (__half2*)(ws + 6201600);// E*4 -> 5000192
    __half*  xh       = (__half*)(ws + 11201792);// N*F*2 (T1 only)

    hipMemsetAsync(counts, 0, (size_t)N_NODES * sizeof(int), stream);

    int cblk = HALFX ? (N_NODES * F / 4 + 255) / 256   // 6250
                     : (N_EDGES + 255) / 256;          // 4883
    conv_hist_kernel<HALFX><<<cblk, 256, 0, stream>>>((const float4*)x, ei, ew, xh, wpk, idx, counts);
    scan_reduce_kernel<<<NBLK_SCAN, 256, 0, stream>>>(counts, partials);
    scan_apply_kernel<<<NBLK_SCAN, 256, 0, stream>>>(counts, partials, off, cursor);
    int eblk = (N_EDGES + 255) / 256;
    permute_kernel<<<eblk, 256, 0, stream>>>(ei, cursor, idx);
    agg_gemm_kernel<HALFX><<<N_NODES / NPB, 512, 0, stream>>>(
        x, xh, off, idx, ei, wpk, Wsrc, Wdst, bsrc, bdst, outA, outB);
}

extern "C" void kernel_launch(void* const* d_in, const int* in_sizes, int n_in,
                              void* d_out, int out_size, void* d_ws, size_t ws_size,
                              hipStream_t stream) {
    const float* x    = (const float*)d_in[0];
    const int*   ei   = (const int*)d_in[1];
    const float* ew   = (const float*)d_in[2];
    const float* Wsrc = (const float*)d_in[3];
    const float* Wdst = (const float*)d_in[4];
    const float* bsrc = (const float*)d_in[5];
    const float* bdst = (const float*)d_in[6];

    float* outA = (float*)d_out;
    float* outB = (float*)d_out + (size_t)N_NODES * F;

    const size_t REQ_T1 = 24001792;  // with fp16 x copy
    const size_t REQ_T2 = 11201792;  // without

    if (ws_size >= REQ_T1) {
        run_path<true>(x, ei, ew, Wsrc, Wdst, bsrc, bdst, outA, outB, (char*)d_ws, stream);
    } else if (ws_size >= REQ_T2) {
        run_path<false>(x, ei, ew, Wsrc, Wdst, bsrc, bdst, outA, outB, (char*)d_ws, stream);
    } else {
        hipMemsetAsync(d_out, 0, (size_t)out_size * sizeof(float), stream);
        int blocks_scatter = (N_EDGES * 16 + 255) / 256;
        scatter_fallback<<<blocks_scatter, 256, 0, stream>>>((const float4*)x, ei, ew, outA, outB);
        int blocks_mm = (N_NODES * 64 + 255) / 256;
        matmul_fallback<<<blocks_mm, 256, 0, stream>>>(outA, outB, Wsrc, Wdst, bsrc, bdst);
    }
}